// Round 17
// baseline (43.976 us; speedup 1.0000x reference)
//
#include <hip/hip_runtime.h>
#include <hip/hip_bf16.h>
#include <math.h>

#define B 128
#define E 6
#define IN_DIM 1664
#define H_DIM 512
#define OUT_DIM 618
#define ZD 32
#define K2 544

typedef __attribute__((ext_vector_type(8))) short short8;
typedef __attribute__((ext_vector_type(4))) float f32x4;
union U128 { uint4 u4; short8 s8; ushort us[8]; };

__device__ __forceinline__ uint pk2(float a, float b) {   // 2 fp32 -> packed bf16x2
    union { __hip_bfloat162 h2; uint u; } cv;
    cv.h2.x = __float2bfloat16(a);
    cv.h2.y = __float2bfloat16(b);
    return cv.u;                       // compiler: v_cvt_pk_bf16_f32
}
__device__ __forceinline__ float elu1(float x) { return x < 0.f ? expm1f(x) : x; }

// MFMA frag math (HW-validated r3-r16):
//  A frag: lane l -> row base+(l&15), k = 32kb+(l>>4)*8+j
//  B frag: lane l -> col n0+(l&15),   k = 32kb+(l>>4)*8+j
//  C/D: col = l&15, row = (l>>4)*4 + r
// B staging (validated r14): thread (tn=tid&15, tq=tid>>4) stages col n0+tn,
//  k-pair (2tq,2tq+1) as one packed uint at lane ((tq>>2)<<4)|tn, j0=(2tq)&7.
// NEW r17: per-expert accumulators acc[e]; A-frag = bf16(x) UNSCALED, expert
// blend moved to epilogue -> inner loop is pure ds_read+MFMA (no per-step
// conversion VALU). Packed cvt via __float2bfloat16 pairs.

// ---------------------------------------------------------------------------
// init_y1: y1 <- coef-blended b1.
// ---------------------------------------------------------------------------
__global__ __launch_bounds__(256) void init_y1(
    const float* __restrict__ coef, const float* __restrict__ b1,
    float* __restrict__ y1)
{
    const int t = blockIdx.x * 256 + threadIdx.x;    // 16384 = B*H_DIM/4
    const int b = t >> 7, o = (t & 127) << 2;
    float4 v = {0.f, 0.f, 0.f, 0.f};
    #pragma unroll
    for (int e = 0; e < E; ++e) {
        const float c = coef[b * E + e];
        const float4 bb = *reinterpret_cast<const float4*>(b1 + e * H_DIM + o);
        v.x = fmaf(c, bb.x, v.x); v.y = fmaf(c, bb.y, v.y);
        v.z = fmaf(c, bb.z, v.z); v.w = fmaf(c, bb.w, v.w);
    }
    *reinterpret_cast<float4*>(y1 + b * H_DIM + o) = v;
}

// ---------------------------------------------------------------------------
// gemm1: L1. Block tile 64 rows x 16 cols, KPB=4 (24 steps), grid (64, 14):
// y==0 -> bias-init slice for y2+out; y in [1,13] -> split kb0=(y-1)*4.
// A-frags: bf16(x) once per kbi. Inner: ds_read + MFMA into acc[e].
// Epilogue: blend acc[e] with coef, 4 atomicAdds into y1.
// ---------------------------------------------------------------------------
__global__ __launch_bounds__(256) void gemm1(
    const float* __restrict__ x,     // [B][IN_DIM]
    const float* __restrict__ coef,  // [B][E]
    const float* __restrict__ w,     // [E][IN_DIM][H_DIM]
    const float* __restrict__ b2, const float* __restrict__ b3,
    float* __restrict__ y1, float* __restrict__ y2, float* __restrict__ out)
{
    __shared__ ushort bs[24][64][8];                 // 24 KB
    const int tid = threadIdx.x;

    if (blockIdx.y == 0) {                           // ---- init slice ----
        const int t = blockIdx.x * 256 + tid;
        {
            const int b = t >> 7, o = (t & 127) << 2;
            float4 v = {0.f, 0.f, 0.f, 0.f};
            #pragma unroll
            for (int e = 0; e < E; ++e) {
                const float c = coef[b * E + e];
                const float4 bb = *reinterpret_cast<const float4*>(b2 + e * H_DIM + o);
                v.x = fmaf(c, bb.x, v.x); v.y = fmaf(c, bb.y, v.y);
                v.z = fmaf(c, bb.z, v.z); v.w = fmaf(c, bb.w, v.w);
            }
            *reinterpret_cast<float4*>(y2 + b * H_DIM + o) = v;
        }
        for (int i = t; i < B * OUT_DIM; i += 64 * 256) {
            const int b = i / OUT_DIM, o = i - b * OUT_DIM;
            float v = 0.f;
            #pragma unroll
            for (int e = 0; e < E; ++e)
                v = fmaf(coef[b * E + e], b3[e * OUT_DIM + o], v);
            out[i] = v;
        }
        return;
    }

    const int kb0 = (blockIdx.y - 1) * 4;
    const int n0 = (blockIdx.x & 31) * 16, rowbase = (blockIdx.x >> 5) * 64;
    const int l = tid & 63, wv = tid >> 6;
    const int tn = tid & 15, tq = tid >> 4;
    const int lp = ((tq >> 2) << 4) | tn, j0 = (2 * tq) & 7;
    const int rowA = rowbase + wv * 16 + (l & 15);
    const int rowE = rowbase + wv * 16 + ((l >> 4) << 2);
    const int kq = l >> 4;

    // epilogue blend coefs (16-lane broadcast loads)
    float cf[4][E];
    #pragma unroll
    for (int r = 0; r < 4; ++r)
        #pragma unroll
        for (int e = 0; e < E; ++e)
            cf[r][e] = coef[(rowE + r) * E + e];

    // A-frags: bf16(x), once per kbi (unscaled)
    U128 ax[4];
    #pragma unroll
    for (int kbi = 0; kbi < 4; ++kbi) {
        const float* p = x + (size_t)rowA * IN_DIM + (kb0 + kbi) * 32 + kq * 8;
        const float4 a = *reinterpret_cast<const float4*>(p);
        const float4 b = *reinterpret_cast<const float4*>(p + 4);
        uint* au = reinterpret_cast<uint*>(&ax[kbi]);
        au[0] = pk2(a.x, a.y); au[1] = pk2(a.z, a.w);
        au[2] = pk2(b.x, b.y); au[3] = pk2(b.z, b.w);
    }

    // W loads + staging (2 batches of 12 tiles), ONE barrier
    #pragma unroll
    for (int bb = 0; bb < 2; ++bb) {
        float wr[12][2];
        #pragma unroll
        for (int ss = 0; ss < 12; ++ss) {
            const int s = bb * 12 + ss;
            const int e = s % E, kb = kb0 + s / E;
            const float* src = w + ((size_t)e * IN_DIM + kb * 32 + 2 * tq) * H_DIM + n0 + tn;
            wr[ss][0] = src[0];
            wr[ss][1] = src[H_DIM];
        }
        #pragma unroll
        for (int ss = 0; ss < 12; ++ss)
            *reinterpret_cast<uint*>(&bs[bb * 12 + ss][lp][j0]) =
                pk2(wr[ss][0], wr[ss][1]);
    }
    __syncthreads();

    // pure ds_read+MFMA stream, per-expert accumulators
    f32x4 acc[E];
    #pragma unroll
    for (int e = 0; e < E; ++e) acc[e] = {0.f, 0.f, 0.f, 0.f};
    #pragma unroll
    for (int s = 0; s < 24; ++s) {
        const int e = s % E, kbi = s / E;
        U128 b0;
        b0.u4 = *reinterpret_cast<const uint4*>(&bs[s][l][0]);
        acc[e] = __builtin_amdgcn_mfma_f32_16x16x32_bf16(ax[kbi].s8, b0.s8,
                                                         acc[e], 0, 0, 0);
    }

    const int colB = n0 + (l & 15);
    #pragma unroll
    for (int r = 0; r < 4; ++r) {
        float val = 0.f;
        #pragma unroll
        for (int e = 0; e < E; ++e) val = fmaf(cf[r][e], acc[e][r], val);
        atomicAdd(&y1[(size_t)(rowE + r) * H_DIM + colB], val);
    }
}

// ---------------------------------------------------------------------------
// gemm_mid: L2/L3. Block tile 64 x 16, 9 splits (8x2kb + 1 z-split). Same
// per-expert-accumulator scheme; A-frags from elu(yin) or raw z.
// ---------------------------------------------------------------------------
template<int KPB, bool ZS, int NW, bool GUARD>
__device__ __forceinline__ void gemm_mid_body(
    const float* __restrict__ yin,   // [B][H_DIM] accum(+bias) pre-ELU
    const float* __restrict__ coef,  // [B][E]
    const float* __restrict__ z,     // [B][ZD]
    const float* __restrict__ w,     // [E][K2][NW]
    float* __restrict__ yout,        // [B][NW] accum (bias pre-init)
    int n0, int rowbase, int kb0, ushort (*bs)[64][8])
{
    constexpr int NS = E * KPB;
    const int tid = threadIdx.x;
    const int l = tid & 63, wv = tid >> 6;
    const int tn = tid & 15, tq = tid >> 4;
    const int lp = ((tq >> 2) << 4) | tn, j0 = (2 * tq) & 7;
    const int rowA = rowbase + wv * 16 + (l & 15);
    const int rowE = rowbase + wv * 16 + ((l >> 4) << 2);
    const int kq = l >> 4;
    const bool okS = !GUARD || (n0 + tn) < NW;

    // W loads up front
    float wr[NS][2];
    #pragma unroll
    for (int s = 0; s < NS; ++s) {
        const int e = s % E, kb = kb0 + s / E;
        const float* src = w + ((size_t)e * K2 + kb * 32 + 2 * tq) * NW + n0 + tn;
        wr[s][0] = okS ? src[0] : 0.f;
        wr[s][1] = okS ? src[NW] : 0.f;
    }

    // epilogue blend coefs
    float cf[4][E];
    #pragma unroll
    for (int r = 0; r < 4; ++r)
        #pragma unroll
        for (int e = 0; e < E; ++e)
            cf[r][e] = coef[(rowE + r) * E + e];

    // A-frags: bf16(elu(yin)) or bf16(z), once per kbi
    U128 ax[KPB];
    if (ZS) {
        const float* p = z + rowA * ZD + kq * 8;
        const float4 a = *reinterpret_cast<const float4*>(p);
        const float4 b = *reinterpret_cast<const float4*>(p + 4);
        uint* au = reinterpret_cast<uint*>(&ax[0]);
        au[0] = pk2(a.x, a.y); au[1] = pk2(a.z, a.w);
        au[2] = pk2(b.x, b.y); au[3] = pk2(b.z, b.w);
    } else {
        #pragma unroll
        for (int kbi = 0; kbi < KPB; ++kbi) {
            const float* p = yin + (size_t)rowA * H_DIM + (kb0 + kbi) * 32 + kq * 8;
            const float4 a = *reinterpret_cast<const float4*>(p);
            const float4 b = *reinterpret_cast<const float4*>(p + 4);
            uint* au = reinterpret_cast<uint*>(&ax[kbi]);
            au[0] = pk2(elu1(a.x), elu1(a.y)); au[1] = pk2(elu1(a.z), elu1(a.w));
            au[2] = pk2(elu1(b.x), elu1(b.y)); au[3] = pk2(elu1(b.z), elu1(b.w));
        }
    }

    // stage everything, ONE barrier
    #pragma unroll
    for (int s = 0; s < NS; ++s)
        *reinterpret_cast<uint*>(&bs[s][lp][j0]) = pk2(wr[s][0], wr[s][1]);
    __syncthreads();

    // pure ds_read+MFMA stream
    f32x4 acc[E];
    #pragma unroll
    for (int e = 0; e < E; ++e) acc[e] = {0.f, 0.f, 0.f, 0.f};
    #pragma unroll
    for (int s = 0; s < NS; ++s) {
        const int e = s % E, kbi = s / E;
        U128 b0;
        b0.u4 = *reinterpret_cast<const uint4*>(&bs[s][l][0]);
        acc[e] = __builtin_amdgcn_mfma_f32_16x16x32_bf16(ax[kbi].s8, b0.s8,
                                                         acc[e], 0, 0, 0);
    }

    const int colB = n0 + (l & 15);
    if (!GUARD || colB < NW) {
        #pragma unroll
        for (int r = 0; r < 4; ++r) {
            float val = 0.f;
            #pragma unroll
            for (int e = 0; e < E; ++e) val = fmaf(cf[r][e], acc[e][r], val);
            atomicAdd(&yout[(size_t)(rowE + r) * NW + colB], val);
        }
    }
}

__global__ __launch_bounds__(256) void gemm_l2(
    const float* __restrict__ y1, const float* __restrict__ coef,
    const float* __restrict__ z, const float* __restrict__ w2,
    float* __restrict__ y2)
{
    __shared__ ushort bs[12][64][8];                 // 12 KB
    const int n0 = (blockIdx.x & 31) * 16, rowbase = (blockIdx.x >> 5) * 64;
    const int sp = blockIdx.y;
    if (sp < 8)
        gemm_mid_body<2, false, H_DIM, false>(y1, coef, z, w2, y2,
                                              n0, rowbase, sp * 2, bs);
    else
        gemm_mid_body<1, true, H_DIM, false>(y1, coef, z, w2, y2,
                                             n0, rowbase, 16, bs);
}

__global__ __launch_bounds__(256) void gemm_l3(
    const float* __restrict__ y2, const float* __restrict__ coef,
    const float* __restrict__ z, const float* __restrict__ w3,
    float* __restrict__ out)
{
    __shared__ ushort bs[12][64][8];
    const int nt = blockIdx.x % 40, rt = blockIdx.x / 40;   // 40 col-tiles
    const int n0 = nt * 16, rowbase = rt * 64;
    const int sp = blockIdx.y;
    if (sp < 8)
        gemm_mid_body<2, false, OUT_DIM, true>(y2, coef, z, w3, out,
                                               n0, rowbase, sp * 2, bs);
    else
        gemm_mid_body<1, true, OUT_DIM, true>(y2, coef, z, w3, out,
                                              n0, rowbase, 16, bs);
}

extern "C" void kernel_launch(void* const* d_in, const int* in_sizes, int n_in,
                              void* d_out, int out_size, void* d_ws, size_t ws_size,
                              hipStream_t stream)
{
    const float* p_prev = (const float*)d_in[0];
    const float* coef   = (const float*)d_in[1];
    const float* z      = (const float*)d_in[2];
    const float* w1     = (const float*)d_in[3];
    const float* b1     = (const float*)d_in[4];
    const float* w2     = (const float*)d_in[5];
    const float* b2     = (const float*)d_in[6];
    const float* w3     = (const float*)d_in[7];
    const float* b3     = (const float*)d_in[8];
    float* out = (float*)d_out;

    // ws: y1 | y2 (fp32 accumulators, re-initialized every call)
    float* y1 = (float*)d_ws;            // [B][512]
    float* y2 = y1 + (size_t)B * H_DIM;  // [B][512]

    init_y1<<<64, 256, 0, stream>>>(coef, b1, y1);
    gemm1<<<dim3(64, 14), 256, 0, stream>>>(p_prev, coef, w1, b2, b3,
                                            y1, y2, out);
    gemm_l2<<<dim3(64, 9), 256, 0, stream>>>(y1, coef, z, w2, y2);
    gemm_l3<<<dim3(80, 9), 256, 0, stream>>>(y2, coef, z, w3, out);
}